// Round 11
// baseline (274.333 us; speedup 1.0000x reference)
//
#include <hip/hip_runtime.h>

typedef __attribute__((ext_vector_type(8))) short short8;
typedef __attribute__((ext_vector_type(4))) float f32x4;
typedef __attribute__((ext_vector_type(4))) unsigned short ushort4v;
typedef unsigned short ushort;

// Tsit5 tableau as constexpr -> folds to immediates under full stage unroll.
constexpr float kA[6][5] = {
  {0.f, 0.f, 0.f, 0.f, 0.f},
  {0.161f, 0.f, 0.f, 0.f, 0.f},
  {-0.008480655492356989f, 0.335480655492357f, 0.f, 0.f, 0.f},
  {2.8971530571054935f, -6.359448489975075f, 4.3622954328695815f, 0.f, 0.f},
  {5.325864828439257f, -11.748883564062828f, 7.4955393428898365f, -0.09249506636175525f, 0.f},
  {5.86145544294642f, -12.92096931784711f, 8.159367898576159f, -0.071584973281401f, -0.028269050394068383f}
};
constexpr float kC6[6] = {0.f, 0.161f, 0.327f, 0.9f, 0.9800255409045097f, 1.0f};
constexpr float kB[6]  = {0.09646076681806523f, 0.01f, 0.4798896504144996f,
                          1.379008574103742f, -3.290069515436081f, 2.324710524099774f};

#define NSTEPS 49
#define XS 136   // h1/h2 bf16 row stride (272 B)
#define GS 136   // G bf16 row stride

#define MF(a, b, cc) __builtin_amdgcn_mfma_f32_16x16x32_bf16(a, b, cc, 0, 0, 0)

__device__ __forceinline__ ushort f2bf(float f) {
    unsigned u = __builtin_bit_cast(unsigned, f);
    u += 0x7fff + ((u >> 16) & 1);
    return (ushort)(u >> 16);
}
__device__ __forceinline__ float bf2f(short s) {
    return __builtin_bit_cast(float, ((unsigned)(ushort)s) << 16);
}
__device__ __forceinline__ short8 pack_bf8(const float* f) {
    short8 v;
    #pragma unroll
    for (int j = 0; j < 8; ++j) v[j] = (short)f2bf(f[j]);
    return v;
}

// 2-tile transposed MFMA over K=128: out[0..3]=tile0 (rows nb..nb+15), out[4..7]=tile1.
__device__ __forceinline__ void gmm2v(const short8 (&A)[2][4], const ushort* xrow, float (&out)[8]) {
    short8 x0 = *(const short8*)(xrow);
    short8 x1 = *(const short8*)(xrow + 32);
    short8 x2 = *(const short8*)(xrow + 64);
    short8 x3 = *(const short8*)(xrow + 96);
    f32x4 a0 = {0.f,0.f,0.f,0.f}, a1 = {0.f,0.f,0.f,0.f};
    a0 = MF(A[0][0], x0, a0); a1 = MF(A[0][1], x1, a1);
    a0 = MF(A[0][2], x2, a0); a1 = MF(A[0][3], x3, a1);
    a0 = a0 + a1;
    f32x4 b0 = {0.f,0.f,0.f,0.f}, b1 = {0.f,0.f,0.f,0.f};
    b0 = MF(A[1][0], x0, b0); b1 = MF(A[1][1], x1, b1);
    b0 = MF(A[1][2], x2, b0); b1 = MF(A[1][3], x3, b1);
    b0 = b0 + b1;
    #pragma unroll
    for (int r = 0; r < 4; ++r) { out[r] = a0[r]; out[4 + r] = b0[r]; }
}

// h1_S = relu(u + dt*sum_{q<S} a[S][q]*v'_q + t_S*w0t + c_S*dt*g0 + b0)
template<int S>
__device__ __forceinline__ void emit_h1(const float (&u)[8], const float (&w0t)[8],
    const float (&g0)[8], const float (&b0v)[8], const float (&vv)[6][8],
    ushort* sH1p, float tstep, float dtv, int c, int q, int nb0)
{
    const float al = tstep + kC6[S] * dtv;
    const float be = kC6[S] * dtv;
    float acc[8];
    #pragma unroll
    for (int i = 0; i < 8; ++i) acc[i] = u[i] + al * w0t[i] + be * g0[i] + b0v[i];
    #pragma unroll
    for (int qq = 0; qq < S; ++qq) {
        const float dc = dtv * kA[S][qq];
        #pragma unroll
        for (int i = 0; i < 8; ++i) acc[i] += dc * vv[qq][i];
    }
    ushort4v o0, o1;
    #pragma unroll
    for (int r = 0; r < 4; ++r) {
        o0[r] = f2bf(fmaxf(acc[r], 0.f));
        o1[r] = f2bf(fmaxf(acc[4 + r], 0.f));
    }
    *(ushort4v*)(&sH1p[c * XS + nb0 + 4 * q]) = o0;
    *(ushort4v*)(&sH1p[c * XS + nb0 + 16 + 4 * q]) = o1;
}

__device__ __forceinline__ void seg2(const short8 (&A)[2][4], const float (&b1v)[8],
    const ushort* sH1p, ushort* sH2p, int c, int q, int nb0)
{
    float hh[8];
    gmm2v(A, &sH1p[c * XS + q * 8], hh);
    ushort4v o0, o1;
    #pragma unroll
    for (int r = 0; r < 4; ++r) {
        o0[r] = f2bf(fmaxf(hh[r]     + b1v[r],     0.f));
        o1[r] = f2bf(fmaxf(hh[4 + r] + b1v[4 + r], 0.f));
    }
    *(ushort4v*)(&sH2p[c * XS + nb0 + 4 * q]) = o0;
    *(ushort4v*)(&sH2p[c * XS + nb0 + 16 + 4 * q]) = o1;
}

__device__ __forceinline__ void hacc_add(float (&hacc)[8], const ushort* p, float coef) {
    short8 hx = *(const short8*)(p);
    #pragma unroll
    for (int j = 0; j < 8; ++j) hacc[j] += coef * bf2f(hx[j]);
}

// 128 blocks x 512 thr (8 waves), M=16 rows/block. G-fused Tsit5:
//   G = W0y*W2 (bf16, init). Per stage only 2 matmuls and 2 barriers:
//   Seg1[w0-3]: v'_{s-1} = G*h2 (regs) ; h1_s = relu(u + dt*sum a*v' + t*w0t + c*dt*g0 + b0) -> LDS
//       [w4-7]: hacc += b_{s-1}*h2 (fp32 regs)
//   Seg2[w4-7]: h2 = relu(W1*h1 + b1) -> LDS
//   u += dt*(sum_q b_q v'_q + g0) once per step (registers). y never materializes;
//   y_final = y0 + dt*W2*hacc + 49*dt*b2 via one end MFMA.
extern "C" __global__ void __launch_bounds__(512, 1)
node_solve(const float* __restrict__ y0, const float* __restrict__ ts,
           const float* __restrict__ gw0, const float* __restrict__ gb0,
           const float* __restrict__ gw1, const float* __restrict__ gb1,
           const float* __restrict__ gw2, const float* __restrict__ gb2,
           float* __restrict__ out)
{
    __shared__ __align__(16) ushort sH1[16 * XS];
    __shared__ __align__(16) ushort sH2[16 * XS];
    __shared__ __align__(16) ushort sG[128 * GS];

    const int tid  = threadIdx.x;
    const int w    = tid >> 6;
    const int lane = tid & 63;
    const int q    = lane >> 4;
    const int c    = lane & 15;
    const int nb0  = 32 * (w & 3);   // 2-tile col base (both roles)
    const int row0 = blockIdx.x * 16;

    const float ts0 = ts[0];
    const float dtv = ts[1] - ts[0];

    // ---- per-role persistent registers ----
    short8 gA[2][4];            // waves 0-3: G A-frags (2 tiles x K=128)
    short8 w1A[2][4];           // waves 4-7: W1 A-frags
    float  u[8], w0t[8], g0[8], b0v[8], b1v[8];
    float  vv[6][8];
    float  hacc[8];
    #pragma unroll
    for (int i = 0; i < 8; ++i) { hacc[i] = 0.f; u[i]=0.f; w0t[i]=0.f; g0[i]=0.f; b0v[i]=0.f; b1v[i]=0.f; }

    if (w >= 4) {
        // ---- W1 A-frags + b1 ----
        #pragma unroll
        for (int t = 0; t < 2; ++t) {
            const int n = nb0 + 16 * t + c;
            #pragma unroll
            for (int ks = 0; ks < 4; ++ks) {
                float tmp[8];
                *(float4*)(tmp)     = *(const float4*)(&gw1[n * 128 + ks * 32 + q * 8]);
                *(float4*)(tmp + 4) = *(const float4*)(&gw1[n * 128 + ks * 32 + q * 8 + 4]);
                w1A[t][ks] = pack_bf8(tmp);
            }
            float4 bb = *(const float4*)(&gb1[nb0 + 16 * t + 4 * q]);
            b1v[4 * t + 0] = bb.x; b1v[4 * t + 1] = bb.y; b1v[4 * t + 2] = bb.z; b1v[4 * t + 3] = bb.w;
        }
    } else {
        // ---- W0y A-frags (temp), then G = W0y*W2 into sG ----
        short8 w0yA[2][2];
        #pragma unroll
        for (int t = 0; t < 2; ++t) {
            const int n = nb0 + 16 * t + c;
            #pragma unroll
            for (int ks = 0; ks < 2; ++ks) {
                float tmp[8];
                #pragma unroll
                for (int j = 0; j < 8; ++j) tmp[j] = gw0[n * 65 + 1 + ks * 32 + q * 8 + j];
                w0yA[t][ks] = pack_bf8(tmp);
            }
        }
        #pragma unroll 1
        for (int jt = 0; jt < 8; ++jt) {
            short8 bB[2];
            #pragma unroll
            for (int ks = 0; ks < 2; ++ks) {
                float tmp[8];
                #pragma unroll
                for (int jd = 0; jd < 8; ++jd)
                    tmp[jd] = gw2[(32 * ks + 8 * q + jd) * 128 + 16 * jt + c];
                bB[ks] = pack_bf8(tmp);
            }
            #pragma unroll
            for (int t = 0; t < 2; ++t) {
                f32x4 Cg = {0.f,0.f,0.f,0.f};
                Cg = MF(w0yA[t][0], bB[0], Cg);
                Cg = MF(w0yA[t][1], bB[1], Cg);
                #pragma unroll
                for (int r = 0; r < 4; ++r)
                    sG[(nb0 + 16 * t + 4 * q + r) * GS + 16 * jt + c] = f2bf(Cg[r]);
            }
        }
        // ---- g0 = W0y*b2 (broadcast B) ; u0 = W0y*y0^T ----
        {
            short8 bB2[2], bY[2];
            #pragma unroll
            for (int ks = 0; ks < 2; ++ks) {
                float tmp[8];
                *(float4*)(tmp)     = *(const float4*)(&gb2[32 * ks + 8 * q]);
                *(float4*)(tmp + 4) = *(const float4*)(&gb2[32 * ks + 8 * q + 4]);
                bB2[ks] = pack_bf8(tmp);
                *(float4*)(tmp)     = *(const float4*)(&y0[(size_t)(row0 + c) * 64 + 32 * ks + 8 * q]);
                *(float4*)(tmp + 4) = *(const float4*)(&y0[(size_t)(row0 + c) * 64 + 32 * ks + 8 * q + 4]);
                bY[ks] = pack_bf8(tmp);
            }
            #pragma unroll
            for (int t = 0; t < 2; ++t) {
                f32x4 Cg = {0.f,0.f,0.f,0.f};
                Cg = MF(w0yA[t][0], bB2[0], Cg);
                Cg = MF(w0yA[t][1], bB2[1], Cg);
                f32x4 Cu = {0.f,0.f,0.f,0.f};
                Cu = MF(w0yA[t][0], bY[0], Cu);
                Cu = MF(w0yA[t][1], bY[1], Cu);
                #pragma unroll
                for (int r = 0; r < 4; ++r) { g0[4 * t + r] = Cg[r]; u[4 * t + r] = Cu[r]; }
            }
        }
        // ---- w0t (t-column of W0), b0 ----
        #pragma unroll
        for (int t = 0; t < 2; ++t) {
            #pragma unroll
            for (int r = 0; r < 4; ++r)
                w0t[4 * t + r] = gw0[(nb0 + 16 * t + 4 * q + r) * 65];
            float4 bb = *(const float4*)(&gb0[nb0 + 16 * t + 4 * q]);
            b0v[4 * t + 0] = bb.x; b0v[4 * t + 1] = bb.y; b0v[4 * t + 2] = bb.z; b0v[4 * t + 3] = bb.w;
        }
    }

    __syncthreads();   // sG complete

    if (w < 4) {       // load G A-frags from LDS
        #pragma unroll
        for (int t = 0; t < 2; ++t)
            #pragma unroll
            for (int ks = 0; ks < 4; ++ks)
                gA[t][ks] = *(const short8*)(&sG[(nb0 + 16 * t + c) * GS + ks * 32 + q * 8]);
    }

    // ---- prologue: h1_0 of step 0 ----
    if (w < 4) emit_h1<0>(u, w0t, g0, b0v, vv, sH1, ts0, dtv, c, q, nb0);
    __syncthreads();
    if (w >= 4) seg2(w1A, b1v, sH1, sH2, c, q, nb0);
    __syncthreads();

#define STAGE(S)                                                              \
    if (w < 4) {                                                              \
        gmm2v(gA, &sH2[c * XS + q * 8], vv[(S) - 1]);                         \
        emit_h1<S>(u, w0t, g0, b0v, vv, sH1, tstep, dtv, c, q, nb0);          \
    } else {                                                                  \
        hacc_add(hacc, &sH2[c * XS + 32 * (w & 3) + q * 8], kB[(S) - 1]);     \
    }                                                                         \
    __syncthreads();                                                          \
    if (w >= 4) seg2(w1A, b1v, sH1, sH2, c, q, nb0);                          \
    __syncthreads();

    #pragma unroll 1
    for (int step = 0; step < NSTEPS; ++step) {
        const float tstep = ts0 + (float)step * dtv;
        const float tnext = ts0 + (float)(step + 1) * dtv;

        STAGE(1)
        STAGE(2)
        STAGE(3)
        STAGE(4)
        STAGE(5)

        // trailing: consume h2_5 -> v'_5; per-step u update; next step's h1_0
        if (step < NSTEPS - 1) {
            if (w < 4) {
                gmm2v(gA, &sH2[c * XS + q * 8], vv[5]);
                #pragma unroll
                for (int i = 0; i < 8; ++i) {
                    const float s6 = kB[0]*vv[0][i] + kB[1]*vv[1][i] + kB[2]*vv[2][i]
                                   + kB[3]*vv[3][i] + kB[4]*vv[4][i] + kB[5]*vv[5][i] + g0[i];
                    u[i] += dtv * s6;
                }
                emit_h1<0>(u, w0t, g0, b0v, vv, sH1, tnext, dtv, c, q, nb0);
            } else {
                hacc_add(hacc, &sH2[c * XS + 32 * (w & 3) + q * 8], kB[5]);
            }
            __syncthreads();
            if (w >= 4) seg2(w1A, b1v, sH1, sH2, c, q, nb0);
            __syncthreads();
        } else {
            if (w >= 4) hacc_add(hacc, &sH2[c * XS + 32 * (w & 3) + q * 8], kB[5]);
        }
    }

    // ---- epilogue: y_final = y0 + dt*W2*hacc + 49*dt*b2 ----
    if (w >= 4) {
        short8 hv;
        #pragma unroll
        for (int j = 0; j < 8; ++j) hv[j] = (short)f2bf(hacc[j]);
        *(short8*)(&sH1[c * XS + 32 * (w & 3) + q * 8]) = hv;
    }
    __syncthreads();
    if (w < 4) {
        const int db = 16 * w;
        short8 w2A[4];
        #pragma unroll
        for (int ks = 0; ks < 4; ++ks) {
            float tmp[8];
            *(float4*)(tmp)     = *(const float4*)(&gw2[(db + c) * 128 + ks * 32 + q * 8]);
            *(float4*)(tmp + 4) = *(const float4*)(&gw2[(db + c) * 128 + ks * 32 + q * 8 + 4]);
            w2A[ks] = pack_bf8(tmp);
        }
        const ushort* xb = &sH1[c * XS + q * 8];
        short8 x0 = *(const short8*)(xb);
        short8 x1 = *(const short8*)(xb + 32);
        short8 x2 = *(const short8*)(xb + 64);
        short8 x3 = *(const short8*)(xb + 96);
        f32x4 Ca = {0.f,0.f,0.f,0.f}, Cb = {0.f,0.f,0.f,0.f};
        Ca = MF(w2A[0], x0, Ca); Cb = MF(w2A[1], x1, Cb);
        Ca = MF(w2A[2], x2, Ca); Cb = MF(w2A[3], x3, Cb);
        Ca = Ca + Cb;
        float4 y0v = *(const float4*)(&y0[(size_t)(row0 + c) * 64 + db + 4 * q]);
        float4 b2v = *(const float4*)(&gb2[db + 4 * q]);
        float4 res;
        res.x = y0v.x + dtv * Ca[0] + (float)NSTEPS * dtv * b2v.x;
        res.y = y0v.y + dtv * Ca[1] + (float)NSTEPS * dtv * b2v.y;
        res.z = y0v.z + dtv * Ca[2] + (float)NSTEPS * dtv * b2v.z;
        res.w = y0v.w + dtv * Ca[3] + (float)NSTEPS * dtv * b2v.w;
        *(float4*)(&out[(size_t)(row0 + c) * 64 + db + 4 * q]) = res;
    }
}

extern "C" void kernel_launch(void* const* d_in, const int* in_sizes, int n_in,
                              void* d_out, int out_size, void* d_ws, size_t ws_size,
                              hipStream_t stream) {
    const float* y0 = (const float*)d_in[0];
    const float* ts = (const float*)d_in[1];
    const float* w0 = (const float*)d_in[2];
    const float* b0 = (const float*)d_in[3];
    const float* w1 = (const float*)d_in[4];
    const float* b1 = (const float*)d_in[5];
    const float* w2 = (const float*)d_in[6];
    const float* b2 = (const float*)d_in[7];
    float* out = (float*)d_out;

    node_solve<<<dim3(128), dim3(512), 0, stream>>>(y0, ts, w0, b0, w1, b1, w2, b2, out);
}